// Round 11
// baseline (379.322 us; speedup 1.0000x reference)
//
#include <hip/hip_runtime.h>
#include <math.h>

#define B_ 2
#define NA_ 4096
#define NR_ 512
#define D_ 128
#define H_ 8
#define DH_ 16
#define NLOCAL_ 5
#define NIPA_ 4
#define NITER_ 3

typedef _Float16 half2_t __attribute__((ext_vector_type(2)));
typedef _Float16 f16x4 __attribute__((ext_vector_type(4)));
typedef float f32x4 __attribute__((ext_vector_type(4)));

#if __has_builtin(__builtin_amdgcn_fdot2)
#define FDOT2(a, b, c) __builtin_amdgcn_fdot2((a), (b), (c), false)
#else
__device__ __forceinline__ float FDOT2(half2_t a, half2_t b, float c) {
  return c + (float)a.x * (float)b.x + (float)a.y * (float)b.y;
}
#endif

#define MFMA16(a, b, c) __builtin_amdgcn_mfma_f32_16x16x16f16((a), (b), (c), 0, 0, 0)

__device__ __forceinline__ unsigned int pack_h(float a, float b) {
  union { unsigned int u; half2_t h; } x;
  x.h = half2_t{(_Float16)a, (_Float16)b};
  return x.u;
}
__device__ __forceinline__ half2_t u2h(unsigned int u) {
  union { unsigned int u; half2_t h; } x;
  x.u = u;
  return x.h;
}
__device__ __forceinline__ f16x4 mk4(unsigned int a, unsigned int b) {
  union { uint2 u; f16x4 h; } x;
  x.u = make_uint2(a, b);
  return x.h;
}
__device__ __forceinline__ float gelu_tanh(float x) {
  float x3 = x * x * x;
  return 0.5f * x * (1.0f + tanhf(0.7978845608028654f * (x + 0.044715f * x3)));
}

// v^T writer: dims d0=2u,d1=2u+1 of head h, row rr -> vT[h][d][rr] (ushort each)
__device__ __forceinline__ void store_vT(unsigned int* vw, int h, int u, int rr,
                                         float b0, float b1) {
  unsigned int pk = pack_h(b0, b1);
  unsigned short* vt16 = (unsigned short*)vw;
  vt16[((h * 16 + 2 * u) << 10) + rr] = (unsigned short)(pk & 0xffffu);
  vt16[((h * 16 + 2 * u + 1) << 10) + rr] = (unsigned short)(pk >> 16);
}

// ============ setup: weight pack + weff + pooling + frame init + ts4g0 ============
__global__ __launch_bounds__(256) void k_setup(
    const float* __restrict__ coords, const int* __restrict__ atype,
    const int* __restrict__ rtype, const int* __restrict__ res_map,
    const float* __restrict__ rots_bad, const float* __restrict__ trans_bad,
    const float* __restrict__ res_mask,
    const float* __restrict__ atom_emb, const float* __restrict__ res_emb,
    const float* __restrict__ coord_W, const float* __restrict__ coord_b,
    const float* __restrict__ local_W, const float* __restrict__ pair_W,
    const float* __restrict__ pair_b, const float* __restrict__ Wq,
    const float* __restrict__ Wk, const float* __restrict__ Wv, const float* __restrict__ Wb,
    const float* __restrict__ Wo, float* __restrict__ feats0, float* __restrict__ weff,
    float* __restrict__ beff, float* __restrict__ curR, float* __restrict__ curT0,
    float4* __restrict__ ts4g0, unsigned int* __restrict__ lwh,
    unsigned int* __restrict__ qkvh, unsigned int* __restrict__ woh) {
  int tid = threadIdx.x, bid = blockIdx.x;
  int gtid = (bid << 8) + tid;
  for (int t = gtid; t < 172032; t += 65536) {
    if (t < 40960) {
      int c = t & 127, kk = (t >> 7) & 63, l = t >> 13;
      const float* s = local_W + (size_t)l * 16384 + (2 * kk) * 128 + c;
      lwh[t] = pack_h(s[0], s[128]);
    } else if (t < 139264) {
      int t2 = t - 40960;
      int c = t2 & 127, kk = (t2 >> 7) & 63, lm = t2 >> 13;
      int l = lm / 3, m = lm % 3;
      const float* base = (m == 0) ? Wq : ((m == 1) ? Wk : Wv);
      const float* s = base + (size_t)l * 16384 + (2 * kk) * 128 + c;
      qkvh[t2] = pack_h(s[0], s[128]);
    } else {
      int t3 = t - 139264;
      int c = t3 & 127, kk = (t3 >> 7) & 63, l = t3 >> 13;
      const float* s = Wo + (size_t)l * 16384 + (2 * kk) * 128 + c;
      woh[t3] = pack_h(s[0], s[128]);
    }
  }
  if (gtid < 160) {
    int l = gtid / 40, rest = gtid % 40;
    int c = rest / 8, h = rest & 7;
    const float* row = (c < 4) ? (pair_W + c * D_) : pair_b;
    float acc = 0.f;
    for (int d = 0; d < D_; d++) acc += row[d] * Wb[l * D_ * H_ + d * H_ + h];
    if (c < 4) weff[l * 32 + c * 8 + h] = acc;
    else beff[l * 8 + h] = acc;
  }
  if (gtid < 9216) curR[gtid] = rots_bad[gtid];
  else if (gtid < 12288) curT0[gtid - 9216] = trans_bad[gtid - 9216];
  if (gtid < 1024)
    ts4g0[gtid] = make_float4(trans_bad[gtid * 3], trans_bad[gtid * 3 + 1],
                              trans_bad[gtid * 3 + 2], res_mask[gtid]);
  for (int rp = 0; rp < 2; rp++) {
    int row = (bid << 2) + (rp << 1) + (tid >> 7);
    int d = tid & 127;
    int b = row >> 9, rr = row & (NR_ - 1);
    const int* rm = res_map + b * NA_;
    int lo = 0, hi = NA_;
    while (lo < hi) { int mid = (lo + hi) >> 1; if (rm[mid] < rr) lo = mid + 1; else hi = mid; }
    int start = lo;
    hi = NA_;
    while (lo < hi) { int mid = (lo + hi) >> 1; if (rm[mid] < rr + 1) lo = mid + 1; else hi = mid; }
    int end = lo;
    float w0 = coord_W[d], w1 = coord_W[D_ + d], w2 = coord_W[2 * D_ + d], cb = coord_b[d];
    float s = 0.f;
    for (int a = start; a < end; a++) {
      int ga = b * NA_ + a;
      s += atom_emb[atype[ga] * D_ + d] + res_emb[rtype[ga] * D_ + d] +
           coords[ga * 3 + 0] * w0 + coords[ga * 3 + 1] * w1 + coords[ga * 3 + 2] * w2 + cb;
    }
    feats0[row * D_ + d] = s / ((float)(end - start) + 1e-8f);
  }
}

// ============ localA: 5-layer MLP + layer-0 QKV ; 4 rows/block (wave = row) ============
__global__ __launch_bounds__(256) void k_localA(
    const float* __restrict__ feats0, const unsigned int* __restrict__ lwh,
    const float* __restrict__ local_b, const unsigned int* __restrict__ qkvh,
    float* __restrict__ featsL, unsigned int* __restrict__ qbU,
    unsigned int* __restrict__ kw, unsigned int* __restrict__ vw) {
  __shared__ unsigned int xh[4][64];
  __shared__ float xsf[4][128];
  int tid = threadIdx.x;
  int w = tid >> 6, cp = tid & 63;
  int row0 = blockIdx.x << 2;
  int row = row0 + w;
  float2 x2 = *(const float2*)(feats0 + (size_t)row * D_ + 2 * cp);
  float y0 = x2.x, y1 = x2.y;
  xsf[w][2 * cp] = y0; xsf[w][2 * cp + 1] = y1;
  xh[w][cp] = pack_h(y0, y1);
  for (int l = 0; l < NLOCAL_; l++) {
    const unsigned int* W = lwh + l * 8192;
    float a0 = 0.f, a1 = 0.f;
#pragma unroll 8
    for (int kk = 0; kk < 64; kk++) {
      uint2 ww = *(const uint2*)(W + kk * 128 + 2 * cp);
      half2_t x = u2h(xh[w][kk]);
      a0 = FDOT2(x, u2h(ww.x), a0);
      a1 = FDOT2(x, u2h(ww.y), a1);
    }
    y0 = gelu_tanh(a0 + local_b[l * D_ + 2 * cp]) + xsf[w][2 * cp];
    y1 = gelu_tanh(a1 + local_b[l * D_ + 2 * cp + 1]) + xsf[w][2 * cp + 1];
    xsf[w][2 * cp] = y0; xsf[w][2 * cp + 1] = y1;  // wave-lockstep safe
    xh[w][cp] = pack_h(y0, y1);
  }
  *(float2*)(featsL + (size_t)row * D_ + 2 * cp) = make_float2(y0, y1);
  __syncthreads();
  if (w < 3) {
    const unsigned int* Wm = qkvh + (size_t)w * 8192;  // layer 0
    float bacc[4][2] = {};
#pragma unroll 8
    for (int kk = 0; kk < 64; kk++) {
      uint2 ww = *(const uint2*)(Wm + kk * 128 + 2 * cp);
#pragma unroll
      for (int r = 0; r < 4; r++) {
        half2_t x = u2h(xh[r][kk]);
        bacc[r][0] = FDOT2(x, u2h(ww.x), bacc[r][0]);
        bacc[r][1] = FDOT2(x, u2h(ww.y), bacc[r][1]);
      }
    }
    int h = cp >> 3, u = cp & 7;
#pragma unroll
    for (int r = 0; r < 4; r++) {
      int rr = row0 + r;
      if (w == 0) qbU[rr * 64 + cp] = pack_h(bacc[r][0], bacc[r][1]);
      else if (w == 1) kw[((h << 10) + rr) * 8 + u] = pack_h(bacc[r][0], bacc[r][1]);
      else store_vT(vw, h, u, rr, bacc[r][0], bacc[r][1]);
    }
  }
}

// ============ fused IPA layer: grid 64, block=(b,qt16), 8 waves = 8 heads ============
__global__ __launch_bounds__(512) void k_layer(
    unsigned int* __restrict__ qbU, const unsigned int* __restrict__ kr,
    const unsigned int* __restrict__ vtg, unsigned int* __restrict__ kw,
    unsigned int* __restrict__ vw, const float4* __restrict__ ts4g,
    const float* __restrict__ weff, const float* __restrict__ beff,
    const unsigned int* __restrict__ woh, const unsigned int* __restrict__ qkvh,
    const float* __restrict__ bo, const float* __restrict__ featsIn,
    float* __restrict__ featsW, const float* __restrict__ featsL,
    const float* __restrict__ curT_r, float* __restrict__ curT_w,
    float4* __restrict__ ts4g_w, float* __restrict__ curR,
    const float* __restrict__ res_mask, const float* __restrict__ head_W,
    const float* __restrict__ head_b, int l, int lastLayer, int doQ0) {
  __shared__ uint2 rel4[16][513];   // f16x4(rx,ry,rz,dist); pad 513 -> 2 lanes/bank
  __shared__ float msk[NR_];
  __shared__ float osf[16][129];    // attention out, all heads; pad 129
  __shared__ float xsf[16][128];    // wave-private rows
  __shared__ unsigned int xh[16][64];
  int tid = threadIdx.x, bid = blockIdx.x;  // grid 64
  int b = bid >> 5, qt = bid & 31;
  int row0 = (b << 9) + qt * 16;

  // ---- phase A: shared rel/dist table (head-independent) ----
  {
    float4 tj4 = ts4g[(b << 9) + tid];
    msk[tid] = tj4.w;
#pragma unroll
    for (int e = 0; e < 16; e++) {
      float4 tq = ts4g[row0 + e];
      float rx = tq.x - tj4.x, ry = tq.y - tj4.y, rz = tq.z - tj4.z;
      float dist = sqrtf(rx * rx + ry * ry + rz * rz);
      rel4[e][tid] = make_uint2(pack_h(rx, ry), pack_h(rz, dist));
    }
  }
  __syncthreads();

  // ---- phase B: MFMA attention, wave = head ----
  int w = tid >> 6, lane = tid & 63;
  int h = w;
  int lrow = lane & 15, lgrp = lane >> 4;
  {
    int qrow = row0 + lrow;
    const uint2 qp = *(const uint2*)(qbU + (size_t)qrow * 64 + h * 8 + lgrp * 2);
    f16x4 qf = mk4(qp.x, qp.y);
    float c0 = weff[l * 32 + h], c1 = weff[l * 32 + 8 + h];
    float c2 = weff[l * 32 + 16 + h], c3 = weff[l * 32 + 24 + h];
    float be = beff[l * 8 + h];
    half2_t wh0{(_Float16)c0, (_Float16)c1};
    half2_t wh1{(_Float16)c2, (_Float16)c3};
    const unsigned int* kbase = kr + ((size_t)((h << 10) + (b << 9))) * 8;
    const unsigned int* vbase = vtg + (((h * 16 + lrow) << 9) + (b << 8));
    f32x4 zero = {0.f, 0.f, 0.f, 0.f};
    f32x4 oacc = zero;
    float lsum = 0.f;
#pragma unroll 4
    for (int jt = 0; jt < 32; jt++) {
      int jr = jt * 16 + lrow;
      uint2 kp = *(const uint2*)(kbase + jr * 8 + lgrp * 2);
      f16x4 kf = mk4(kp.x, kp.y);
      f32x4 s = MFMA16(kf, qf, zero);   // lane: S[q=lrow][j=jt*16+4*lgrp+r]
      f16x4 pv;
#pragma unroll
      for (int r = 0; r < 4; r++) {
        int j = jt * 16 + lgrp * 4 + r;
        uint2 rv = rel4[lrow][j];
        float dot = FDOT2(u2h(rv.y), wh1, FDOT2(u2h(rv.x), wh0, 0.f));
        float L = s[r] * 0.25f + dot + be;
        L = (msk[j] > 0.f) ? L : -1e9f;
        float p = __expf(L);  // shift-free: logits bounded, softmax shift-invariant
        lsum += p;
        pv[r] = (_Float16)p;
      }
      uint2 vp2 = *(const uint2*)(vbase + jt * 8 + lgrp * 2);
      f16x4 vf = mk4(vp2.x, vp2.y);
      oacc = MFMA16(vf, pv, oacc);      // O^T += V^T · P^T
    }
    lsum += __shfl_xor(lsum, 16, 64);
    lsum += __shfl_xor(lsum, 32, 64);
    float inv = 1.f / lsum;
#pragma unroll
    for (int r = 0; r < 4; r++) osf[lrow][h * 16 + lgrp * 4 + r] = oacc[r] * inv;
  }
  __syncthreads();

  // ---- phase C: oproj + residual + {qkv(l+1) | head+frame [+qkv0]}, wave = 2 rows ----
  int cp = lane;
  int r0 = 2 * w, r1 = 2 * w + 1;
  // pack O (wave-private rows)
  xh[r0][cp] = pack_h(osf[r0][2 * cp], osf[r0][2 * cp + 1]);
  xh[r1][cp] = pack_h(osf[r1][2 * cp], osf[r1][2 * cp + 1]);
  {
    const unsigned int* W = woh + (size_t)l * 8192;
    float a[2][2] = {};
#pragma unroll 8
    for (int kk = 0; kk < 64; kk++) {
      uint2 ww = *(const uint2*)(W + kk * 128 + 2 * cp);
      half2_t x0 = u2h(xh[r0][kk]);
      half2_t x1 = u2h(xh[r1][kk]);
      a[0][0] = FDOT2(x0, u2h(ww.x), a[0][0]);
      a[0][1] = FDOT2(x0, u2h(ww.y), a[0][1]);
      a[1][0] = FDOT2(x1, u2h(ww.x), a[1][0]);
      a[1][1] = FDOT2(x1, u2h(ww.y), a[1][1]);
    }
#pragma unroll
    for (int r = 0; r < 2; r++) {
      int rl = r0 + r;
      int row = row0 + rl;
      float f0 = a[r][0] + bo[l * D_ + 2 * cp] + featsIn[(size_t)row * D_ + 2 * cp];
      float f1 = a[r][1] + bo[l * D_ + 2 * cp + 1] + featsIn[(size_t)row * D_ + 2 * cp + 1];
      *(float2*)(featsW + (size_t)row * D_ + 2 * cp) = make_float2(f0, f1);
      xsf[rl][2 * cp] = f0; xsf[rl][2 * cp + 1] = f1;  // wave-private
      xh[rl][cp] = pack_h(f0, f1);
    }
  }
  if (!lastLayer) {
#pragma unroll
    for (int m = 0; m < 3; m++) {
      const unsigned int* Wm = qkvh + (size_t)((l + 1) * 3 + m) * 8192;
      float bacc[2][2] = {};
#pragma unroll 8
      for (int kk = 0; kk < 64; kk++) {
        uint2 ww = *(const uint2*)(Wm + kk * 128 + 2 * cp);
        half2_t x0 = u2h(xh[r0][kk]);
        half2_t x1 = u2h(xh[r1][kk]);
        bacc[0][0] = FDOT2(x0, u2h(ww.x), bacc[0][0]);
        bacc[0][1] = FDOT2(x0, u2h(ww.y), bacc[0][1]);
        bacc[1][0] = FDOT2(x1, u2h(ww.x), bacc[1][0]);
        bacc[1][1] = FDOT2(x1, u2h(ww.y), bacc[1][1]);
      }
      int hh = cp >> 3, u = cp & 7;
#pragma unroll
      for (int r = 0; r < 2; r++) {
        int rr = row0 + r0 + r;
        if (m == 0) qbU[rr * 64 + cp] = pack_h(bacc[r][0], bacc[r][1]);
        else if (m == 1) kw[((hh << 10) + rr) * 8 + u] = pack_h(bacc[r][0], bacc[r][1]);
        else store_vT(vw, hh, u, rr, bacc[r][0], bacc[r][1]);
      }
    }
  } else {
#pragma unroll
    for (int r = 0; r < 2; r++) {
      int rl = r0 + r;
      int row = row0 + rl;
      float f0 = xsf[rl][2 * cp], f1 = xsf[rl][2 * cp + 1];
      float pc[6];
#pragma unroll
      for (int c = 0; c < 6; c++)
        pc[c] = f0 * head_W[(2 * cp) * 6 + c] + f1 * head_W[(2 * cp + 1) * 6 + c];
#pragma unroll
      for (int m = 1; m < 64; m <<= 1)
#pragma unroll
        for (int c = 0; c < 6; c++) pc[c] += __shfl_xor(pc[c], m, 64);
      if (cp == 0) {
        float u[6];
#pragma unroll
        for (int c = 0; c < 6; c++) u[c] = pc[c] + head_b[c];
        float vx = u[0], vy = u[1], vz = u[2];
        float inv = rsqrtf(1.f + vx * vx + vy * vy + vz * vz);
        float qw = inv, qx = vx * inv, qy = vy * inv, qz = vz * inv;
        float Rd[9];
        Rd[0] = 1.f - 2.f * (qy * qy + qz * qz); Rd[1] = 2.f * (qx * qy - qw * qz);
        Rd[2] = 2.f * (qx * qz + qw * qy); Rd[3] = 2.f * (qx * qy + qw * qz);
        Rd[4] = 1.f - 2.f * (qx * qx + qz * qz); Rd[5] = 2.f * (qy * qz - qw * qx);
        Rd[6] = 2.f * (qx * qz - qw * qy); Rd[7] = 2.f * (qy * qz + qw * qx);
        Rd[8] = 1.f - 2.f * (qx * qx + qy * qy);
        float Ro[9];
#pragma unroll
        for (int c = 0; c < 9; c++) Ro[c] = curR[row * 9 + c];
        float Rn[9];
#pragma unroll
        for (int i2 = 0; i2 < 3; i2++)
#pragma unroll
          for (int kk = 0; kk < 3; kk++)
            Rn[i2 * 3 + kk] = Rd[i2 * 3 + 0] * Ro[0 * 3 + kk] +
                              Rd[i2 * 3 + 1] * Ro[1 * 3 + kk] +
                              Rd[i2 * 3 + 2] * Ro[2 * 3 + kk];
        float tx = curT_r[row * 3 + 0], ty = curT_r[row * 3 + 1], tz = curT_r[row * 3 + 2];
        float ux = u[3], uy = u[4], uz = u[5];
        float m = res_mask[row];
#pragma unroll
        for (int c = 0; c < 9; c++) curR[row * 9 + c] = Rn[c];
        float ntx = (tx + Rn[0] * ux + Rn[1] * uy + Rn[2] * uz) * m;
        float nty = (ty + Rn[3] * ux + Rn[4] * uy + Rn[5] * uz) * m;
        float ntz = (tz + Rn[6] * ux + Rn[7] * uy + Rn[8] * uz) * m;
        curT_w[row * 3 + 0] = ntx;
        curT_w[row * 3 + 1] = nty;
        curT_w[row * 3 + 2] = ntz;
        ts4g_w[row] = make_float4(ntx, nty, ntz, m);
      }
    }
    if (doQ0) {
      // recompute layer-0 qkv from featsL (constant across iterations)
      {
        float2 fl0 = *(const float2*)(featsL + (size_t)(row0 + r0) * D_ + 2 * cp);
        float2 fl1 = *(const float2*)(featsL + (size_t)(row0 + r1) * D_ + 2 * cp);
        xh[r0][cp] = pack_h(fl0.x, fl0.y);   // wave-private
        xh[r1][cp] = pack_h(fl1.x, fl1.y);
      }
#pragma unroll
      for (int m = 0; m < 3; m++) {
        const unsigned int* Wm = qkvh + (size_t)m * 8192;  // layer 0
        float bacc[2][2] = {};
#pragma unroll 8
        for (int kk = 0; kk < 64; kk++) {
          uint2 ww = *(const uint2*)(Wm + kk * 128 + 2 * cp);
          half2_t x0 = u2h(xh[r0][kk]);
          half2_t x1 = u2h(xh[r1][kk]);
          bacc[0][0] = FDOT2(x0, u2h(ww.x), bacc[0][0]);
          bacc[0][1] = FDOT2(x0, u2h(ww.y), bacc[0][1]);
          bacc[1][0] = FDOT2(x1, u2h(ww.x), bacc[1][0]);
          bacc[1][1] = FDOT2(x1, u2h(ww.y), bacc[1][1]);
        }
        int hh = cp >> 3, u = cp & 7;
#pragma unroll
        for (int r = 0; r < 2; r++) {
          int rr = row0 + r0 + r;
          if (m == 0) qbU[rr * 64 + cp] = pack_h(bacc[r][0], bacc[r][1]);
          else if (m == 1) kw[((hh << 10) + rr) * 8 + u] = pack_h(bacc[r][0], bacc[r][1]);
          else store_vT(vw, hh, u, rr, bacc[r][0], bacc[r][1]);
        }
      }
    }
  }
}

// ============ final frame composition + output ============
__global__ void k_final(const float* __restrict__ coords, const int* __restrict__ res_map,
                        const float* __restrict__ rots_bad, const float* __restrict__ trans_bad,
                        const float* __restrict__ curR, const float* __restrict__ curT,
                        float* __restrict__ out) {
  int a = blockIdx.x * blockDim.x + threadIdx.x;
  if (a < B_ * NR_) {
#pragma unroll
    for (int c = 0; c < 9; c++) out[a * 9 + c] = curR[a * 9 + c];
    out[B_ * NR_ * 9 + a * 3 + 0] = curT[a * 3 + 0];
    out[B_ * NR_ * 9 + a * 3 + 1] = curT[a * 3 + 1];
    out[B_ * NR_ * 9 + a * 3 + 2] = curT[a * 3 + 2];
  }
  if (a >= B_ * NA_) return;
  int b = a / NA_;
  int r = b * NR_ + res_map[a];
  float x0 = coords[a * 3 + 0], x1 = coords[a * 3 + 1], x2 = coords[a * 3 + 2];
  float R0[9], Rc[9];
#pragma unroll
  for (int c = 0; c < 9; c++) { R0[c] = rots_bad[r * 9 + c]; Rc[c] = curR[r * 9 + c]; }
  float t0x = trans_bad[r * 3 + 0], t0y = trans_bad[r * 3 + 1], t0z = trans_bad[r * 3 + 2];
  float dx = x0 - t0x, dy = x1 - t0y, dz = x2 - t0z;
  float lx = R0[0] * dx + R0[3] * dy + R0[6] * dz;
  float ly = R0[1] * dx + R0[4] * dy + R0[7] * dz;
  float lz = R0[2] * dx + R0[5] * dy + R0[8] * dz;
  float tcx = curT[r * 3 + 0], tcy = curT[r * 3 + 1], tcz = curT[r * 3 + 2];
  float fx = Rc[0] * lx + Rc[3] * ly + Rc[6] * lz + tcx;
  float fy = Rc[1] * lx + Rc[4] * ly + Rc[7] * lz + tcy;
  float fz = Rc[2] * lx + Rc[5] * ly + Rc[8] * lz + tcz;
  int off = B_ * NR_ * 12;
  out[off + a * 3 + 0] = fx;
  out[off + a * 3 + 1] = fy;
  out[off + a * 3 + 2] = fz;
}

extern "C" void kernel_launch(void* const* d_in, const int* in_sizes, int n_in,
                              void* d_out, int out_size, void* d_ws, size_t ws_size,
                              hipStream_t stream) {
  const float* coords    = (const float*)d_in[0];
  const int*   atype     = (const int*)d_in[1];
  const int*   rtype     = (const int*)d_in[2];
  // d_in[3] = mask (unused)
  const float* res_mask  = (const float*)d_in[4];
  const int*   res_map   = (const int*)d_in[5];
  const float* rots_bad  = (const float*)d_in[6];
  const float* trans_bad = (const float*)d_in[7];
  const float* atom_emb  = (const float*)d_in[8];
  const float* res_emb   = (const float*)d_in[9];
  const float* coord_W   = (const float*)d_in[10];
  const float* coord_b   = (const float*)d_in[11];
  const float* local_W   = (const float*)d_in[12];
  const float* local_b   = (const float*)d_in[13];
  const float* pair_W    = (const float*)d_in[14];
  const float* pair_b    = (const float*)d_in[15];
  const float* Wq        = (const float*)d_in[16];
  const float* Wk        = (const float*)d_in[17];
  const float* Wv        = (const float*)d_in[18];
  const float* Wb        = (const float*)d_in[19];
  const float* Wo        = (const float*)d_in[20];
  const float* bo        = (const float*)d_in[21];
  const float* head_W    = (const float*)d_in[22];
  const float* head_b    = (const float*)d_in[23];

  float* ws = (float*)d_ws;
  float* feats0 = ws;  ws += 131072;
  float* featsL = ws;  ws += 131072;
  float* featsW = ws;  ws += 131072;
  float* weff   = ws;  ws += 128;
  float* beff   = ws;  ws += 32;
  float* curR   = ws;  ws += 9216;
  float* curT0  = ws;  ws += 3072;
  float* curT1  = ws;  ws += 3072;
  float4* ts4g0 = (float4*)ws;  ws += 4096;
  float4* ts4g1 = (float4*)ws;  ws += 4096;
  unsigned int* wu = (unsigned int*)ws;
  unsigned int* qbU = wu;  wu += 65536;
  unsigned int* kbA = wu;  wu += 65536;
  unsigned int* vtA = wu;  wu += 65536;
  unsigned int* kbB = wu;  wu += 65536;
  unsigned int* vtB = wu;  wu += 65536;
  unsigned int* lwh  = wu; wu += 40960;
  unsigned int* qkvh = wu; wu += 98304;
  unsigned int* woh  = wu; wu += 32768;
  float* out = (float*)d_out;

  k_setup<<<256, 256, 0, stream>>>(coords, atype, rtype, res_map, rots_bad, trans_bad,
                                   res_mask, atom_emb, res_emb, coord_W, coord_b, local_W,
                                   pair_W, pair_b, Wq, Wk, Wv, Wb, Wo, feats0, weff, beff,
                                   curR, curT0, ts4g0, lwh, qkvh, woh);
  k_localA<<<256, 256, 0, stream>>>(feats0, lwh, local_b, qkvh, featsL, qbU, kbA, vtA);

  for (int iter = 0; iter < NITER_; iter++) {
    float* Tr = (iter & 1) ? curT1 : curT0;
    float* Tw = (iter & 1) ? curT0 : curT1;
    float4* Gr = (iter & 1) ? ts4g1 : ts4g0;
    float4* Gw = (iter & 1) ? ts4g0 : ts4g1;
    for (int l = 0; l < NIPA_; l++) {
      unsigned int* krd = (l & 1) ? kbB : kbA;
      unsigned int* vrd = (l & 1) ? vtB : vtA;
      unsigned int* kwr = (l & 1) ? kbA : kbB;
      unsigned int* vwr = (l & 1) ? vtA : vtB;
      k_layer<<<64, 512, 0, stream>>>(qbU, krd, vrd, kwr, vwr, Gr, weff, beff, woh, qkvh,
                                      bo, (l == 0) ? featsL : featsW, featsW, featsL,
                                      Tr, Tw, Gw, curR, res_mask, head_W, head_b, l,
                                      (l == NIPA_ - 1) ? 1 : 0,
                                      (l == NIPA_ - 1 && iter < NITER_ - 1) ? 1 : 0);
    }
  }
  k_final<<<(B_ * NA_ + 255) / 256, 256, 0, stream>>>(coords, res_map, rots_bad, trans_bad,
                                                      curR, curT1, out);
}

// Round 12
// 216.594 us; speedup vs baseline: 1.7513x; 1.7513x over previous
//
#include <hip/hip_runtime.h>
#include <math.h>

#define B_ 2
#define NA_ 4096
#define NR_ 512
#define D_ 128
#define H_ 8
#define DH_ 16
#define NLOCAL_ 5
#define NIPA_ 4
#define NITER_ 3

typedef _Float16 half2_t __attribute__((ext_vector_type(2)));
typedef _Float16 f16x4 __attribute__((ext_vector_type(4)));
typedef float f32x4 __attribute__((ext_vector_type(4)));

#if __has_builtin(__builtin_amdgcn_fdot2)
#define FDOT2(a, b, c) __builtin_amdgcn_fdot2((a), (b), (c), false)
#else
__device__ __forceinline__ float FDOT2(half2_t a, half2_t b, float c) {
  return c + (float)a.x * (float)b.x + (float)a.y * (float)b.y;
}
#endif

#define MFMA16(a, b, c) __builtin_amdgcn_mfma_f32_16x16x16f16((a), (b), (c), 0, 0, 0)

__device__ __forceinline__ unsigned int pack_h(float a, float b) {
  union { unsigned int u; half2_t h; } x;
  x.h = half2_t{(_Float16)a, (_Float16)b};
  return x.u;
}
__device__ __forceinline__ half2_t u2h(unsigned int u) {
  union { unsigned int u; half2_t h; } x;
  x.u = u;
  return x.h;
}
__device__ __forceinline__ f16x4 mk4(unsigned int a, unsigned int b) {
  union { uint2 u; f16x4 h; } x;
  x.u = make_uint2(a, b);
  return x.h;
}
__device__ __forceinline__ float gelu_tanh(float x) {
  float x3 = x * x * x;
  return 0.5f * x * (1.0f + tanhf(0.7978845608028654f * (x + 0.044715f * x3)));
}

// v^T writer: dims d0=2u,d1=2u+1 of head h, row rr -> vT[h][d][rr] (ushort each)
__device__ __forceinline__ void store_vT(unsigned int* vw, int h, int u, int rr,
                                         float b0, float b1) {
  unsigned int pk = pack_h(b0, b1);
  unsigned short* vt16 = (unsigned short*)vw;
  vt16[((h * 16 + 2 * u) << 10) + rr] = (unsigned short)(pk & 0xffffu);
  vt16[((h * 16 + 2 * u + 1) << 10) + rr] = (unsigned short)(pk >> 16);
}

// ============ setup: weight pack + weff + pooling + frame init + ts4g0 ============
__global__ __launch_bounds__(256) void k_setup(
    const float* __restrict__ coords, const int* __restrict__ atype,
    const int* __restrict__ rtype, const int* __restrict__ res_map,
    const float* __restrict__ rots_bad, const float* __restrict__ trans_bad,
    const float* __restrict__ res_mask,
    const float* __restrict__ atom_emb, const float* __restrict__ res_emb,
    const float* __restrict__ coord_W, const float* __restrict__ coord_b,
    const float* __restrict__ local_W, const float* __restrict__ pair_W,
    const float* __restrict__ pair_b, const float* __restrict__ Wq,
    const float* __restrict__ Wk, const float* __restrict__ Wv, const float* __restrict__ Wb,
    const float* __restrict__ Wo, float* __restrict__ feats0, float* __restrict__ weff,
    float* __restrict__ beff, float* __restrict__ curR, float* __restrict__ curT0,
    float4* __restrict__ ts4g0, unsigned int* __restrict__ lwh,
    unsigned int* __restrict__ qkvh, unsigned int* __restrict__ woh) {
  int tid = threadIdx.x, bid = blockIdx.x;
  int gtid = (bid << 8) + tid;
  for (int t = gtid; t < 172032; t += 65536) {
    if (t < 40960) {
      int c = t & 127, kk = (t >> 7) & 63, l = t >> 13;
      const float* s = local_W + (size_t)l * 16384 + (2 * kk) * 128 + c;
      lwh[t] = pack_h(s[0], s[128]);
    } else if (t < 139264) {
      int t2 = t - 40960;
      int c = t2 & 127, kk = (t2 >> 7) & 63, lm = t2 >> 13;
      int l = lm / 3, m = lm % 3;
      const float* base = (m == 0) ? Wq : ((m == 1) ? Wk : Wv);
      const float* s = base + (size_t)l * 16384 + (2 * kk) * 128 + c;
      qkvh[t2] = pack_h(s[0], s[128]);
    } else {
      int t3 = t - 139264;
      int c = t3 & 127, kk = (t3 >> 7) & 63, l = t3 >> 13;
      const float* s = Wo + (size_t)l * 16384 + (2 * kk) * 128 + c;
      woh[t3] = pack_h(s[0], s[128]);
    }
  }
  if (gtid < 160) {
    int l = gtid / 40, rest = gtid % 40;
    int c = rest / 8, h = rest & 7;
    const float* row = (c < 4) ? (pair_W + c * D_) : pair_b;
    float acc = 0.f;
    for (int d = 0; d < D_; d++) acc += row[d] * Wb[l * D_ * H_ + d * H_ + h];
    if (c < 4) weff[l * 32 + c * 8 + h] = acc;
    else beff[l * 8 + h] = acc;
  }
  if (gtid < 9216) curR[gtid] = rots_bad[gtid];
  else if (gtid < 12288) curT0[gtid - 9216] = trans_bad[gtid - 9216];
  if (gtid < 1024)
    ts4g0[gtid] = make_float4(trans_bad[gtid * 3], trans_bad[gtid * 3 + 1],
                              trans_bad[gtid * 3 + 2], res_mask[gtid]);
  for (int rp = 0; rp < 2; rp++) {
    int row = (bid << 2) + (rp << 1) + (tid >> 7);
    int d = tid & 127;
    int b = row >> 9, rr = row & (NR_ - 1);
    const int* rm = res_map + b * NA_;
    int lo = 0, hi = NA_;
    while (lo < hi) { int mid = (lo + hi) >> 1; if (rm[mid] < rr) lo = mid + 1; else hi = mid; }
    int start = lo;
    hi = NA_;
    while (lo < hi) { int mid = (lo + hi) >> 1; if (rm[mid] < rr + 1) lo = mid + 1; else hi = mid; }
    int end = lo;
    float w0 = coord_W[d], w1 = coord_W[D_ + d], w2 = coord_W[2 * D_ + d], cb = coord_b[d];
    float s = 0.f;
    for (int a = start; a < end; a++) {
      int ga = b * NA_ + a;
      s += atom_emb[atype[ga] * D_ + d] + res_emb[rtype[ga] * D_ + d] +
           coords[ga * 3 + 0] * w0 + coords[ga * 3 + 1] * w1 + coords[ga * 3 + 2] * w2 + cb;
    }
    feats0[row * D_ + d] = s / ((float)(end - start) + 1e-8f);
  }
}

// ============ localA: 5-layer MLP + layer-0 QKV ; 4 rows/block (wave = row) ============
__global__ __launch_bounds__(256) void k_localA(
    const float* __restrict__ feats0, const unsigned int* __restrict__ lwh,
    const float* __restrict__ local_b, const unsigned int* __restrict__ qkvh,
    float* __restrict__ featsL, unsigned int* __restrict__ qbU,
    unsigned int* __restrict__ kw, unsigned int* __restrict__ vw) {
  __shared__ unsigned int xh[4][64];
  __shared__ float xsf[4][128];
  int tid = threadIdx.x;
  int w = tid >> 6, cp = tid & 63;
  int row0 = blockIdx.x << 2;
  int row = row0 + w;
  float2 x2 = *(const float2*)(feats0 + (size_t)row * D_ + 2 * cp);
  float y0 = x2.x, y1 = x2.y;
  xsf[w][2 * cp] = y0; xsf[w][2 * cp + 1] = y1;
  xh[w][cp] = pack_h(y0, y1);
  for (int l = 0; l < NLOCAL_; l++) {
    const unsigned int* W = lwh + l * 8192;
    float a0 = 0.f, a1 = 0.f;
#pragma unroll 8
    for (int kk = 0; kk < 64; kk++) {
      uint2 ww = *(const uint2*)(W + kk * 128 + 2 * cp);
      half2_t x = u2h(xh[w][kk]);
      a0 = FDOT2(x, u2h(ww.x), a0);
      a1 = FDOT2(x, u2h(ww.y), a1);
    }
    y0 = gelu_tanh(a0 + local_b[l * D_ + 2 * cp]) + xsf[w][2 * cp];
    y1 = gelu_tanh(a1 + local_b[l * D_ + 2 * cp + 1]) + xsf[w][2 * cp + 1];
    xsf[w][2 * cp] = y0; xsf[w][2 * cp + 1] = y1;  // wave-lockstep safe
    xh[w][cp] = pack_h(y0, y1);
  }
  *(float2*)(featsL + (size_t)row * D_ + 2 * cp) = make_float2(y0, y1);
  __syncthreads();
  if (w < 3) {
    const unsigned int* Wm = qkvh + (size_t)w * 8192;  // layer 0
    float bacc[4][2] = {};
#pragma unroll 8
    for (int kk = 0; kk < 64; kk++) {
      uint2 ww = *(const uint2*)(Wm + kk * 128 + 2 * cp);
#pragma unroll
      for (int r = 0; r < 4; r++) {
        half2_t x = u2h(xh[r][kk]);
        bacc[r][0] = FDOT2(x, u2h(ww.x), bacc[r][0]);
        bacc[r][1] = FDOT2(x, u2h(ww.y), bacc[r][1]);
      }
    }
    int h = cp >> 3, u = cp & 7;
#pragma unroll
    for (int r = 0; r < 4; r++) {
      int rr = row0 + r;
      if (w == 0) qbU[rr * 64 + cp] = pack_h(bacc[r][0], bacc[r][1]);
      else if (w == 1) kw[((h << 10) + rr) * 8 + u] = pack_h(bacc[r][0], bacc[r][1]);
      else store_vT(vw, h, u, rr, bacc[r][0], bacc[r][1]);
    }
  }
}

// ============ MFMA attention: grid 512, block=(b,h,qt), 4 waves j-split ============
// ts4 staged in LDS (kills L1 thrash from K/V streaming); pre[j] = be - c.t_j
__global__ __launch_bounds__(256) void k_attn(
    const unsigned int* __restrict__ qbU, const unsigned int* __restrict__ kr,
    const unsigned int* __restrict__ vtg, const float4* __restrict__ ts4g,
    const float* __restrict__ weff, const float* __restrict__ beff,
    float* __restrict__ ob, int l) {
  __shared__ float4 ts4[NR_];
  __shared__ float pre[NR_];
  __shared__ float osum[4][64][5];
  int tid = threadIdx.x, bid = blockIdx.x;  // grid 512
  int w = tid >> 6, lane = tid & 63;
  int qt = bid & 31, bh = bid >> 5;
  int b = bh >> 3, h = bh & 7;
  float c0 = weff[l * 32 + h], c1 = weff[l * 32 + 8 + h];
  float c2 = weff[l * 32 + 16 + h], c3 = weff[l * 32 + 24 + h];
  float be = beff[l * 8 + h];
  for (int idx = tid; idx < NR_; idx += 256) {
    float4 t4 = ts4g[(b << 9) + idx];
    ts4[idx] = t4;
    pre[idx] = be - (c0 * t4.x + c1 * t4.y + c2 * t4.z);
  }
  __syncthreads();
  int lrow = lane & 15, lgrp = lane >> 4;
  int qrow = (b << 9) + qt * 16 + lrow;
  const uint2 qp = *(const uint2*)(qbU + (size_t)qrow * 64 + h * 8 + lgrp * 2);
  f16x4 qf = mk4(qp.x, qp.y);
  float4 ti = ts4[qt * 16 + lrow];
  float cti = c0 * ti.x + c1 * ti.y + c2 * ti.z;
  const unsigned int* kbase = kr + ((size_t)((h << 10) + (b << 9))) * 8;
  const unsigned int* vbase = vtg + (((h * 16 + lrow) << 9) + (b << 8));
  f32x4 zero = {0.f, 0.f, 0.f, 0.f};
  f32x4 oacc = zero;
  float lsum = 0.f;
#pragma unroll
  for (int jj = 0; jj < 8; jj++) {
    int jt = w * 8 + jj;
    int jr = jt * 16 + lrow;
    uint2 kp = *(const uint2*)(kbase + jr * 8 + lgrp * 2);
    f16x4 kf = mk4(kp.x, kp.y);
    f32x4 s = MFMA16(kf, qf, zero);   // lane: S[q=lrow][j=jt*16+4*lgrp+r]
    f16x4 pv;
#pragma unroll
    for (int r = 0; r < 4; r++) {
      int j = jt * 16 + lgrp * 4 + r;
      float4 tj = ts4[j];             // LDS broadcast (j is lrow-independent)
      float rx = ti.x - tj.x, ry = ti.y - tj.y, rz = ti.z - tj.z;
      float dist = sqrtf(rx * rx + ry * ry + rz * rz);
      // L = s*0.25 + c.(ti-tj) + c3*dist + be  ==  s*0.25 + cti + pre[j] + c3*dist
      float L = s[r] * 0.25f + cti + pre[j] + c3 * dist;
      L = (tj.w > 0.f) ? L : -1e9f;
      float p = __expf(L);  // shift-free: logits bounded, softmax shift-invariant
      lsum += p;
      pv[r] = (_Float16)p;
    }
    uint2 vp2 = *(const uint2*)(vbase + jt * 8 + lgrp * 2);
    f16x4 vf = mk4(vp2.x, vp2.y);
    oacc = MFMA16(vf, pv, oacc);      // O^T += V^T · P^T
  }
  lsum += __shfl_xor(lsum, 16, 64);
  lsum += __shfl_xor(lsum, 32, 64);
  float* o = osum[w][lane];
  o[0] = oacc[0]; o[1] = oacc[1]; o[2] = oacc[2]; o[3] = oacc[3]; o[4] = lsum;
  __syncthreads();
  if (w == 0) {
    float s0 = 0.f, s1 = 0.f, s2 = 0.f, s3 = 0.f, sl = 0.f;
#pragma unroll
    for (int r = 0; r < 4; r++) {
      const float* p = osum[r][lane];
      s0 += p[0]; s1 += p[1]; s2 += p[2]; s3 += p[3]; sl += p[4];
    }
    float inv = 1.f / sl;
    float4 o4 = make_float4(s0 * inv, s1 * inv, s2 * inv, s3 * inv);
    *(float4*)(ob + (size_t)qrow * D_ + h * DH_ + lgrp * 4) = o4;
  }
}

// ============ oproj + residual + {qkv(l+1) | head+frame [+qkv0]} ; 2 rows/block ============
__global__ __launch_bounds__(256) void k_oproj(
    const float* __restrict__ ob, const unsigned int* __restrict__ woh,
    const float* __restrict__ bo, const unsigned int* __restrict__ qkvh,
    const float* __restrict__ featsIn, float* __restrict__ featsW,
    const float* __restrict__ featsL, unsigned int* __restrict__ qbU,
    unsigned int* __restrict__ kw, unsigned int* __restrict__ vw,
    const float* __restrict__ curT_r, float* __restrict__ curT_w,
    float4* __restrict__ ts4g_w, float* __restrict__ curR,
    const float* __restrict__ res_mask, const float* __restrict__ head_W,
    const float* __restrict__ head_b, int l, int lastLayer, int doQ0) {
  __shared__ float part[4][2][128];
  __shared__ float xsf[2][128];
  __shared__ unsigned int xh[2][64];
  int tid = threadIdx.x;
  int w = tid >> 6, cp = tid & 63;
  int row0 = blockIdx.x << 1;  // grid 512
  if (w < 2) {
    float2 o2 = *(const float2*)(ob + (size_t)(row0 + w) * D_ + 2 * cp);
    xh[w][cp] = pack_h(o2.x, o2.y);
  }
  __syncthreads();
  // phase 1: oproj, k-split across 4 waves, 2 rows per wave
  {
    const unsigned int* W = woh + (size_t)l * 8192 + (w * 16) * 128;
    float a[2][2] = {};
#pragma unroll
    for (int kk = 0; kk < 16; kk++) {
      uint2 ww = *(const uint2*)(W + kk * 128 + 2 * cp);
#pragma unroll
      for (int r = 0; r < 2; r++) {
        half2_t x = u2h(xh[r][w * 16 + kk]);
        a[r][0] = FDOT2(x, u2h(ww.x), a[r][0]);
        a[r][1] = FDOT2(x, u2h(ww.y), a[r][1]);
      }
    }
#pragma unroll
    for (int r = 0; r < 2; r++) {
      part[w][r][2 * cp] = a[r][0];
      part[w][r][2 * cp + 1] = a[r][1];
    }
  }
  __syncthreads();
  {
    int r = tid >> 7, c = tid & 127;
    float f = part[0][r][c] + part[1][r][c] + part[2][r][c] + part[3][r][c] +
              bo[l * D_ + c] + featsIn[(size_t)(row0 + r) * D_ + c];
    featsW[(size_t)(row0 + r) * D_ + c] = f;
    xsf[r][c] = f;
  }
  __syncthreads();
  if (w < 2) xh[w][cp] = pack_h(xsf[w][2 * cp], xsf[w][2 * cp + 1]);
  __syncthreads();
  if (!lastLayer) {
    if (w < 3) {
      const unsigned int* Wm = qkvh + (size_t)((l + 1) * 3 + w) * 8192;
      float bacc[2][2] = {};
#pragma unroll 8
      for (int kk = 0; kk < 64; kk++) {
        uint2 ww = *(const uint2*)(Wm + kk * 128 + 2 * cp);
#pragma unroll
        for (int r = 0; r < 2; r++) {
          half2_t x = u2h(xh[r][kk]);
          bacc[r][0] = FDOT2(x, u2h(ww.x), bacc[r][0]);
          bacc[r][1] = FDOT2(x, u2h(ww.y), bacc[r][1]);
        }
      }
      int h = cp >> 3, u = cp & 7;
#pragma unroll
      for (int r = 0; r < 2; r++) {
        int rr = row0 + r;
        if (w == 0) qbU[rr * 64 + cp] = pack_h(bacc[r][0], bacc[r][1]);
        else if (w == 1) kw[((h << 10) + rr) * 8 + u] = pack_h(bacc[r][0], bacc[r][1]);
        else store_vT(vw, h, u, rr, bacc[r][0], bacc[r][1]);
      }
    }
  } else {
    if (w < 2) {
      int row = row0 + w;
      float f0 = xsf[w][2 * cp], f1 = xsf[w][2 * cp + 1];
      float pc[6];
#pragma unroll
      for (int c = 0; c < 6; c++)
        pc[c] = f0 * head_W[(2 * cp) * 6 + c] + f1 * head_W[(2 * cp + 1) * 6 + c];
#pragma unroll
      for (int m = 1; m < 64; m <<= 1)
#pragma unroll
        for (int c = 0; c < 6; c++) pc[c] += __shfl_xor(pc[c], m, 64);
      if (cp == 0) {
        float u[6];
#pragma unroll
        for (int c = 0; c < 6; c++) u[c] = pc[c] + head_b[c];
        float vx = u[0], vy = u[1], vz = u[2];
        float inv = rsqrtf(1.f + vx * vx + vy * vy + vz * vz);
        float qw = inv, qx = vx * inv, qy = vy * inv, qz = vz * inv;
        float Rd[9];
        Rd[0] = 1.f - 2.f * (qy * qy + qz * qz); Rd[1] = 2.f * (qx * qy - qw * qz);
        Rd[2] = 2.f * (qx * qz + qw * qy); Rd[3] = 2.f * (qx * qy + qw * qz);
        Rd[4] = 1.f - 2.f * (qx * qx + qz * qz); Rd[5] = 2.f * (qy * qz - qw * qx);
        Rd[6] = 2.f * (qx * qz - qw * qy); Rd[7] = 2.f * (qy * qz + qw * qx);
        Rd[8] = 1.f - 2.f * (qx * qx + qy * qy);
        float Ro[9];
#pragma unroll
        for (int c = 0; c < 9; c++) Ro[c] = curR[row * 9 + c];
        float Rn[9];
#pragma unroll
        for (int i2 = 0; i2 < 3; i2++)
#pragma unroll
          for (int kk = 0; kk < 3; kk++)
            Rn[i2 * 3 + kk] = Rd[i2 * 3 + 0] * Ro[0 * 3 + kk] +
                              Rd[i2 * 3 + 1] * Ro[1 * 3 + kk] +
                              Rd[i2 * 3 + 2] * Ro[2 * 3 + kk];
        float tx = curT_r[row * 3 + 0], ty = curT_r[row * 3 + 1], tz = curT_r[row * 3 + 2];
        float ux = u[3], uy = u[4], uz = u[5];
        float m = res_mask[row];
#pragma unroll
        for (int c = 0; c < 9; c++) curR[row * 9 + c] = Rn[c];
        float ntx = (tx + Rn[0] * ux + Rn[1] * uy + Rn[2] * uz) * m;
        float nty = (ty + Rn[3] * ux + Rn[4] * uy + Rn[5] * uz) * m;
        float ntz = (tz + Rn[6] * ux + Rn[7] * uy + Rn[8] * uz) * m;
        curT_w[row * 3 + 0] = ntx;
        curT_w[row * 3 + 1] = nty;
        curT_w[row * 3 + 2] = ntz;
        ts4g_w[row] = make_float4(ntx, nty, ntz, m);
      }
    }
    if (doQ0) {
      if (w < 2) {
        float2 fl = *(const float2*)(featsL + (size_t)(row0 + w) * D_ + 2 * cp);
        xh[w][cp] = pack_h(fl.x, fl.y);
      }
      __syncthreads();
      if (w < 3) {
        const unsigned int* Wm = qkvh + (size_t)w * 8192;  // layer 0
        float bacc[2][2] = {};
#pragma unroll 8
        for (int kk = 0; kk < 64; kk++) {
          uint2 ww = *(const uint2*)(Wm + kk * 128 + 2 * cp);
#pragma unroll
          for (int r = 0; r < 2; r++) {
            half2_t x = u2h(xh[r][kk]);
            bacc[r][0] = FDOT2(x, u2h(ww.x), bacc[r][0]);
            bacc[r][1] = FDOT2(x, u2h(ww.y), bacc[r][1]);
          }
        }
        int h = cp >> 3, u = cp & 7;
#pragma unroll
        for (int r = 0; r < 2; r++) {
          int rr = row0 + r;
          if (w == 0) qbU[rr * 64 + cp] = pack_h(bacc[r][0], bacc[r][1]);
          else if (w == 1) kw[((h << 10) + rr) * 8 + u] = pack_h(bacc[r][0], bacc[r][1]);
          else store_vT(vw, h, u, rr, bacc[r][0], bacc[r][1]);
        }
      }
    }
  }
}

// ============ final frame composition + output ============
__global__ void k_final(const float* __restrict__ coords, const int* __restrict__ res_map,
                        const float* __restrict__ rots_bad, const float* __restrict__ trans_bad,
                        const float* __restrict__ curR, const float* __restrict__ curT,
                        float* __restrict__ out) {
  int a = blockIdx.x * blockDim.x + threadIdx.x;
  if (a < B_ * NR_) {
#pragma unroll
    for (int c = 0; c < 9; c++) out[a * 9 + c] = curR[a * 9 + c];
    out[B_ * NR_ * 9 + a * 3 + 0] = curT[a * 3 + 0];
    out[B_ * NR_ * 9 + a * 3 + 1] = curT[a * 3 + 1];
    out[B_ * NR_ * 9 + a * 3 + 2] = curT[a * 3 + 2];
  }
  if (a >= B_ * NA_) return;
  int b = a / NA_;
  int r = b * NR_ + res_map[a];
  float x0 = coords[a * 3 + 0], x1 = coords[a * 3 + 1], x2 = coords[a * 3 + 2];
  float R0[9], Rc[9];
#pragma unroll
  for (int c = 0; c < 9; c++) { R0[c] = rots_bad[r * 9 + c]; Rc[c] = curR[r * 9 + c]; }
  float t0x = trans_bad[r * 3 + 0], t0y = trans_bad[r * 3 + 1], t0z = trans_bad[r * 3 + 2];
  float dx = x0 - t0x, dy = x1 - t0y, dz = x2 - t0z;
  float lx = R0[0] * dx + R0[3] * dy + R0[6] * dz;
  float ly = R0[1] * dx + R0[4] * dy + R0[7] * dz;
  float lz = R0[2] * dx + R0[5] * dy + R0[8] * dz;
  float tcx = curT[r * 3 + 0], tcy = curT[r * 3 + 1], tcz = curT[r * 3 + 2];
  float fx = Rc[0] * lx + Rc[3] * ly + Rc[6] * lz + tcx;
  float fy = Rc[1] * lx + Rc[4] * ly + Rc[7] * lz + tcy;
  float fz = Rc[2] * lx + Rc[5] * ly + Rc[8] * lz + tcz;
  int off = B_ * NR_ * 12;
  out[off + a * 3 + 0] = fx;
  out[off + a * 3 + 1] = fy;
  out[off + a * 3 + 2] = fz;
}

extern "C" void kernel_launch(void* const* d_in, const int* in_sizes, int n_in,
                              void* d_out, int out_size, void* d_ws, size_t ws_size,
                              hipStream_t stream) {
  const float* coords    = (const float*)d_in[0];
  const int*   atype     = (const int*)d_in[1];
  const int*   rtype     = (const int*)d_in[2];
  // d_in[3] = mask (unused)
  const float* res_mask  = (const float*)d_in[4];
  const int*   res_map   = (const int*)d_in[5];
  const float* rots_bad  = (const float*)d_in[6];
  const float* trans_bad = (const float*)d_in[7];
  const float* atom_emb  = (const float*)d_in[8];
  const float* res_emb   = (const float*)d_in[9];
  const float* coord_W   = (const float*)d_in[10];
  const float* coord_b   = (const float*)d_in[11];
  const float* local_W   = (const float*)d_in[12];
  const float* local_b   = (const float*)d_in[13];
  const float* pair_W    = (const float*)d_in[14];
  const float* pair_b    = (const float*)d_in[15];
  const float* Wq        = (const float*)d_in[16];
  const float* Wk        = (const float*)d_in[17];
  const float* Wv        = (const float*)d_in[18];
  const float* Wb        = (const float*)d_in[19];
  const float* Wo        = (const float*)d_in[20];
  const float* bo        = (const float*)d_in[21];
  const float* head_W    = (const float*)d_in[22];
  const float* head_b    = (const float*)d_in[23];

  float* ws = (float*)d_ws;
  float* ob     = ws;  ws += 131072;   // aliased: feats0 (setup/localA), then attn out
  float* feats0 = ob;
  float* featsL = ws;  ws += 131072;
  float* featsW = ws;  ws += 131072;
  float* weff   = ws;  ws += 128;
  float* beff   = ws;  ws += 32;
  float* curR   = ws;  ws += 9216;
  float* curT0  = ws;  ws += 3072;
  float* curT1  = ws;  ws += 3072;
  float4* ts4g0 = (float4*)ws;  ws += 4096;
  float4* ts4g1 = (float4*)ws;  ws += 4096;
  unsigned int* wu = (unsigned int*)ws;
  unsigned int* qbU = wu;  wu += 65536;
  unsigned int* kbA = wu;  wu += 65536;
  unsigned int* vtA = wu;  wu += 65536;
  unsigned int* kbB = wu;  wu += 65536;
  unsigned int* vtB = wu;  wu += 65536;
  unsigned int* lwh  = wu; wu += 40960;
  unsigned int* qkvh = wu; wu += 98304;
  unsigned int* woh  = wu; wu += 32768;
  float* out = (float*)d_out;

  k_setup<<<256, 256, 0, stream>>>(coords, atype, rtype, res_map, rots_bad, trans_bad,
                                   res_mask, atom_emb, res_emb, coord_W, coord_b, local_W,
                                   pair_W, pair_b, Wq, Wk, Wv, Wb, Wo, feats0, weff, beff,
                                   curR, curT0, ts4g0, lwh, qkvh, woh);
  k_localA<<<256, 256, 0, stream>>>(feats0, lwh, local_b, qkvh, featsL, qbU, kbA, vtA);

  for (int iter = 0; iter < NITER_; iter++) {
    float* Tr = (iter & 1) ? curT1 : curT0;
    float* Tw = (iter & 1) ? curT0 : curT1;
    float4* Gr = (iter & 1) ? ts4g1 : ts4g0;
    float4* Gw = (iter & 1) ? ts4g0 : ts4g1;
    for (int l = 0; l < NIPA_; l++) {
      unsigned int* krd = (l & 1) ? kbB : kbA;
      unsigned int* vrd = (l & 1) ? vtB : vtA;
      unsigned int* kwr = (l & 1) ? kbA : kbB;
      unsigned int* vwr = (l & 1) ? vtA : vtB;
      k_attn<<<512, 256, 0, stream>>>(qbU, krd, vrd, Gr, weff, beff, ob, l);
      k_oproj<<<512, 256, 0, stream>>>(ob, woh, bo, qkvh, (l == 0) ? featsL : featsW,
                                       featsW, featsL, qbU, kwr, vwr, Tr, Tw, Gw, curR,
                                       res_mask, head_W, head_b, l,
                                       (l == NIPA_ - 1) ? 1 : 0,
                                       (l == NIPA_ - 1 && iter < NITER_ - 1) ? 1 : 0);
    }
  }
  k_final<<<(B_ * NA_ + 255) / 256, 256, 0, stream>>>(coords, res_map, rots_bad, trans_bad,
                                                      curR, curT1, out);
}